// Round 1
// baseline (4903.769 us; speedup 1.0000x reference)
//
#include <hip/hip_runtime.h>

#define D 64
#define LAYERS 3

// ---- monotone float<->uint mapping for atomicMax-based segment max ----
__device__ __forceinline__ unsigned fmap(float f) {
    unsigned u = __float_as_uint(f);
    return (u & 0x80000000u) ? ~u : (u | 0x80000000u);
}
__device__ __forceinline__ float funmap(unsigned u) {
    return (u & 0x80000000u) ? __uint_as_float(u & 0x7fffffffu)
                             : __uint_as_float(~u);
}

// Fused projections: q = x@Wq+bq, k = x@Wk+bk, v = x@Wv+bv, skip = x@Ws+bs.
// skip is written into `hout` (the layer output buffer); aggregation later
// atomically adds into hout, giving out = agg + skip without extra buffers.
__global__ __launch_bounds__(256) void proj_kernel(
    const float* __restrict__ x,
    const float* __restrict__ Wq, const float* __restrict__ bq,
    const float* __restrict__ Wk, const float* __restrict__ bk,
    const float* __restrict__ Wv, const float* __restrict__ bv,
    const float* __restrict__ Ws, const float* __restrict__ bs,
    float* __restrict__ q, float* __restrict__ k,
    float* __restrict__ v, float* __restrict__ hout, int N)
{
    __shared__ float xs[16][D];
    const int block_row = blockIdx.x * 16;
    const int t = threadIdx.x;
    // stage 16 rows of x
    for (int i = t; i < 16 * D; i += 256) {
        int r = i >> 6, c = i & 63;
        int row = block_row + r;
        xs[r][c] = (row < N) ? x[row * D + c] : 0.0f;
    }
    __syncthreads();

    const int col  = t & 63;
    const int rsub = t >> 6;           // 0..3 -> rows rsub*4 .. rsub*4+3
    float aq[4], ak[4], av[4], as_[4];
    const float bqc = bq[col], bkc = bk[col], bvc = bv[col], bsc = bs[col];
#pragma unroll
    for (int j = 0; j < 4; ++j) { aq[j] = bqc; ak[j] = bkc; av[j] = bvc; as_[j] = bsc; }

    for (int i = 0; i < D; ++i) {
        const float wq = Wq[i * D + col];
        const float wk = Wk[i * D + col];
        const float wv = Wv[i * D + col];
        const float ws = Ws[i * D + col];
#pragma unroll
        for (int j = 0; j < 4; ++j) {
            const float xi = xs[rsub * 4 + j][i];
            aq[j]  = fmaf(xi, wq, aq[j]);
            ak[j]  = fmaf(xi, wk, ak[j]);
            av[j]  = fmaf(xi, wv, av[j]);
            as_[j] = fmaf(xi, ws, as_[j]);
        }
    }
#pragma unroll
    for (int j = 0; j < 4; ++j) {
        const int row = block_row + rsub * 4 + j;
        if (row < N) {
            q[row * D + col]    = aq[j];
            k[row * D + col]    = ak[j];
            v[row * D + col]    = av[j];
            hout[row * D + col] = as_[j];
        }
    }
}

// alpha[e] = <q[dst], k[src]> / 8 ; fused segment-max via mapped atomicMax.
__global__ __launch_bounds__(256) void alpha_kernel(
    const float* __restrict__ q, const float* __restrict__ k,
    const int* __restrict__ src, const int* __restrict__ dst,
    float* __restrict__ alpha, unsigned* __restrict__ mmax, int E)
{
    const int t = threadIdx.x;
    const int lane = t & 15;
    const int e = blockIdx.x * 16 + (t >> 4);
    if (e >= E) return;
    const int s = src[e], d = dst[e];
    const float4 qv = *(const float4*)(q + d * D + lane * 4);
    const float4 kv = *(const float4*)(k + s * D + lane * 4);
    float p = qv.x * kv.x + qv.y * kv.y + qv.z * kv.z + qv.w * kv.w;
    p += __shfl_xor(p, 1);
    p += __shfl_xor(p, 2);
    p += __shfl_xor(p, 4);
    p += __shfl_xor(p, 8);
    p *= 0.125f;  // 1/sqrt(64)
    if (lane == 0) {
        alpha[e] = p;
        atomicMax(mmax + d, fmap(p));
    }
}

// alpha[e] <- exp(alpha[e] - m[dst[e]]) ; denom[dst] += e
__global__ __launch_bounds__(256) void exp_kernel(
    float* __restrict__ alpha, const unsigned* __restrict__ mmax,
    const int* __restrict__ dst, float* __restrict__ denom, int E)
{
    const int e = blockIdx.x * 256 + threadIdx.x;
    if (e >= E) return;
    const int d = dst[e];
    const float m = funmap(mmax[d]);
    const float ex = expf(alpha[e] - m);
    alpha[e] = ex;
    unsafeAtomicAdd(denom + d, ex);
}

// hout[dst] += (e/denom[dst]) * v[src]
__global__ __launch_bounds__(256) void agg_kernel(
    const float* __restrict__ alpha, const float* __restrict__ denom,
    const float* __restrict__ v,
    const int* __restrict__ src, const int* __restrict__ dst,
    float* __restrict__ hout, int E)
{
    const int t = threadIdx.x;
    const int lane = t & 15;
    const int e = blockIdx.x * 16 + (t >> 4);
    if (e >= E) return;
    const int s = src[e], d = dst[e];
    const float w = alpha[e] / (denom[d] + 1e-16f);
    const float4 vv = *(const float4*)(v + s * D + lane * 4);
    float* o = hout + d * D + lane * 4;
    unsafeAtomicAdd(o + 0, w * vv.x);
    unsafeAtomicAdd(o + 1, w * vv.y);
    unsafeAtomicAdd(o + 2, w * vv.z);
    unsafeAtomicAdd(o + 3, w * vv.w);
}

__global__ __launch_bounds__(256) void relu_kernel(float* __restrict__ h, int n)
{
    const int i = blockIdx.x * 256 + threadIdx.x;
    if (i < n) h[i] = fmaxf(h[i], 0.0f);
}

extern "C" void kernel_launch(void* const* d_in, const int* in_sizes, int n_in,
                              void* d_out, int out_size, void* d_ws, size_t ws_size,
                              hipStream_t stream)
{
    const float* x   = (const float*)d_in[0];
    const int* ei    = (const int*)d_in[1];
    // d_in[2] = edge_type: unused by the reference
    const float* Wq  = (const float*)d_in[3];
    const float* bq  = (const float*)d_in[4];
    const float* Wk  = (const float*)d_in[5];
    const float* bk  = (const float*)d_in[6];
    const float* Wv  = (const float*)d_in[7];
    const float* bv  = (const float*)d_in[8];
    const float* Ws  = (const float*)d_in[9];
    const float* bs  = (const float*)d_in[10];

    const int N = in_sizes[0] / D;
    const int E = in_sizes[2];
    const int* src = ei;
    const int* dst = ei + E;

    // workspace layout (floats)
    float* ws = (float*)d_ws;
    float* q     = ws;                 // N*D
    float* k     = q + (size_t)N * D;  // N*D
    float* v     = k + (size_t)N * D;  // N*D
    float* h0    = v + (size_t)N * D;  // N*D
    float* h1    = h0 + (size_t)N * D; // N*D
    float* alpha = h1 + (size_t)N * D; // E
    unsigned* mmax = (unsigned*)(alpha + E); // N
    float* denom = (float*)(mmax + N);       // N

    const int proj_blocks  = (N + 15) / 16;
    const int edge_blocks  = (E + 15) / 16;
    const int edge_blocks1 = (E + 255) / 256;
    const int relu_blocks  = (N * D + 255) / 256;

    const float* cur = x;
    for (int l = 0; l < LAYERS; ++l) {
        float* hout = (l == LAYERS - 1) ? (float*)d_out : (l & 1 ? h1 : h0);

        hipMemsetAsync(mmax,  0, (size_t)N * 4, stream);
        hipMemsetAsync(denom, 0, (size_t)N * 4, stream);

        proj_kernel<<<proj_blocks, 256, 0, stream>>>(
            cur,
            Wq + (size_t)l * D * D, bq + (size_t)l * D,
            Wk + (size_t)l * D * D, bk + (size_t)l * D,
            Wv + (size_t)l * D * D, bv + (size_t)l * D,
            Ws + (size_t)l * D * D, bs + (size_t)l * D,
            q, k, v, hout, N);

        alpha_kernel<<<edge_blocks, 256, 0, stream>>>(q, k, src, dst, alpha, mmax, E);
        exp_kernel<<<edge_blocks1, 256, 0, stream>>>(alpha, mmax, dst, denom, E);
        agg_kernel<<<edge_blocks, 256, 0, stream>>>(alpha, denom, v, src, dst, hout, E);

        if (l < LAYERS - 1) {
            relu_kernel<<<relu_blocks, 256, 0, stream>>>(hout, N * D);
        }
        cur = hout;
    }
}

// Round 2
// 736.763 us; speedup vs baseline: 6.6558x; 6.6558x over previous
//
#include <hip/hip_runtime.h>

#define D 64
#define LAYERS 3

// ---------------- projections ----------------
// q = x@Wq+bq, k = x@Wk+bk, v = x@Wv+bv, skip = x@Ws+bs (skip -> hout).
__global__ __launch_bounds__(256) void proj_kernel(
    const float* __restrict__ x,
    const float* __restrict__ Wq, const float* __restrict__ bq,
    const float* __restrict__ Wk, const float* __restrict__ bk,
    const float* __restrict__ Wv, const float* __restrict__ bv,
    const float* __restrict__ Ws, const float* __restrict__ bs,
    float* __restrict__ q, float* __restrict__ k,
    float* __restrict__ v, float* __restrict__ hout, int N)
{
    __shared__ float xs[16][D];
    const int block_row = blockIdx.x * 16;
    const int t = threadIdx.x;
    for (int i = t; i < 16 * D; i += 256) {
        int r = i >> 6, c = i & 63;
        int row = block_row + r;
        xs[r][c] = (row < N) ? x[row * D + c] : 0.0f;
    }
    __syncthreads();

    const int col  = t & 63;
    const int rsub = t >> 6;
    float aq[4], ak[4], av[4], as_[4];
    const float bqc = bq[col], bkc = bk[col], bvc = bv[col], bsc = bs[col];
#pragma unroll
    for (int j = 0; j < 4; ++j) { aq[j] = bqc; ak[j] = bkc; av[j] = bvc; as_[j] = bsc; }

    for (int i = 0; i < D; ++i) {
        const float wq = Wq[i * D + col];
        const float wk = Wk[i * D + col];
        const float wv = Wv[i * D + col];
        const float ws = Ws[i * D + col];
#pragma unroll
        for (int j = 0; j < 4; ++j) {
            const float xi = xs[rsub * 4 + j][i];
            aq[j]  = fmaf(xi, wq, aq[j]);
            ak[j]  = fmaf(xi, wk, ak[j]);
            av[j]  = fmaf(xi, wv, av[j]);
            as_[j] = fmaf(xi, ws, as_[j]);
        }
    }
#pragma unroll
    for (int j = 0; j < 4; ++j) {
        const int row = block_row + rsub * 4 + j;
        if (row < N) {
            q[row * D + col]    = aq[j];
            k[row * D + col]    = ak[j];
            v[row * D + col]    = av[j];
            hout[row * D + col] = as_[j];
        }
    }
}

// ---------------- counting sort of edges by dst ----------------
__global__ __launch_bounds__(256) void hist_kernel(
    const int* __restrict__ dst, int* __restrict__ counts, int E)
{
    const int e = blockIdx.x * 256 + threadIdx.x;
    if (e < E) atomicAdd(counts + dst[e], 1);
}

// per-block exclusive scan (256 elements), emit block total
__global__ __launch_bounds__(256) void scan_block_kernel(
    const int* __restrict__ counts, int* __restrict__ offs,
    int* __restrict__ bsum, int N)
{
    __shared__ int tmp[256];
    const int t = threadIdx.x;
    const int i = blockIdx.x * 256 + t;
    const int val = (i < N) ? counts[i] : 0;
    tmp[t] = val;
    __syncthreads();
    for (int off = 1; off < 256; off <<= 1) {
        int x = (t >= off) ? tmp[t - off] : 0;
        __syncthreads();
        tmp[t] += x;
        __syncthreads();
    }
    if (i < N) offs[i] = tmp[t] - val;      // exclusive
    if (t == 255) bsum[blockIdx.x] = tmp[255];
}

// single-block exclusive scan of the block sums (nb <= 512)
__global__ __launch_bounds__(512) void scan_bsum_kernel(int* __restrict__ bsum, int nb)
{
    __shared__ int tmp[512];
    const int t = threadIdx.x;
    const int val = (t < nb) ? bsum[t] : 0;
    tmp[t] = val;
    __syncthreads();
    for (int off = 1; off < 512; off <<= 1) {
        int x = (t >= off) ? tmp[t - off] : 0;
        __syncthreads();
        tmp[t] += x;
        __syncthreads();
    }
    if (t < nb) bsum[t] = tmp[t] - val;     // exclusive
}

__global__ __launch_bounds__(256) void add_bsum_kernel(
    int* __restrict__ offs, const int* __restrict__ bsum, int N)
{
    const int i = blockIdx.x * 256 + threadIdx.x;
    if (i < N) offs[i] += bsum[blockIdx.x];
}

__global__ __launch_bounds__(256) void scatter_kernel(
    const int* __restrict__ src, const int* __restrict__ dst,
    const int* __restrict__ offs, int* __restrict__ cursor,
    int* __restrict__ esrc, int E)
{
    const int e = blockIdx.x * 256 + threadIdx.x;
    if (e >= E) return;
    const int d = dst[e];
    const int pos = offs[d] + atomicAdd(cursor + d, 1);
    esrc[pos] = src[e];
}

// ---------------- fused per-node attention ----------------
// 16 lanes per node (4 nodes per wave). Online softmax over the node's
// dst-sorted incoming edges; no atomics. hout already holds the skip term.
__global__ __launch_bounds__(256) void node_kernel(
    const float* __restrict__ q, const float* __restrict__ k,
    const float* __restrict__ v, const int* __restrict__ esrc,
    const int* __restrict__ offs, const int* __restrict__ counts,
    float* __restrict__ hout, int N, int do_relu)
{
    const int t = threadIdx.x;
    const int lane = t & 15;
    const int node = blockIdx.x * 16 + (t >> 4);
    if (node >= N) return;

    const int start = offs[node];
    const int end   = start + counts[node];

    const float4 qv = *(const float4*)(q + (size_t)node * D + lane * 4);

    float m = -INFINITY, ssum = 0.0f;
    float4 acc = make_float4(0.0f, 0.0f, 0.0f, 0.0f);

    int s = (start < end) ? esrc[start] : 0;
    for (int j = start; j < end; ++j) {
        const float4 kv = *(const float4*)(k + (size_t)s * D + lane * 4);
        const float4 vv = *(const float4*)(v + (size_t)s * D + lane * 4);
        const int snext = (j + 1 < end) ? esrc[j + 1] : 0;

        float p = kv.x * qv.x + kv.y * qv.y + kv.z * qv.z + kv.w * qv.w;
        p += __shfl_xor(p, 1);
        p += __shfl_xor(p, 2);
        p += __shfl_xor(p, 4);
        p += __shfl_xor(p, 8);
        p *= 0.125f;  // 1/sqrt(64)

        if (p > m) {                       // uniform across the 16-lane group
            const float sc = __expf(m - p);
            ssum *= sc;
            acc.x *= sc; acc.y *= sc; acc.z *= sc; acc.w *= sc;
            m = p;
        }
        const float w = __expf(p - m);
        ssum += w;
        acc.x = fmaf(w, vv.x, acc.x);
        acc.y = fmaf(w, vv.y, acc.y);
        acc.z = fmaf(w, vv.z, acc.z);
        acc.w = fmaf(w, vv.w, acc.w);
        s = snext;
    }

    const float inv = 1.0f / (ssum + 1e-16f);
    float* o = hout + (size_t)node * D + lane * 4;
    float4 ov = *(const float4*)o;
    ov.x = fmaf(acc.x, inv, ov.x);
    ov.y = fmaf(acc.y, inv, ov.y);
    ov.z = fmaf(acc.z, inv, ov.z);
    ov.w = fmaf(acc.w, inv, ov.w);
    if (do_relu) {
        ov.x = fmaxf(ov.x, 0.0f); ov.y = fmaxf(ov.y, 0.0f);
        ov.z = fmaxf(ov.z, 0.0f); ov.w = fmaxf(ov.w, 0.0f);
    }
    *(float4*)o = ov;
}

extern "C" void kernel_launch(void* const* d_in, const int* in_sizes, int n_in,
                              void* d_out, int out_size, void* d_ws, size_t ws_size,
                              hipStream_t stream)
{
    const float* x   = (const float*)d_in[0];
    const int* ei    = (const int*)d_in[1];
    const float* Wq  = (const float*)d_in[3];
    const float* bq  = (const float*)d_in[4];
    const float* Wk  = (const float*)d_in[5];
    const float* bk  = (const float*)d_in[6];
    const float* Wv  = (const float*)d_in[7];
    const float* bv  = (const float*)d_in[8];
    const float* Ws  = (const float*)d_in[9];
    const float* bs  = (const float*)d_in[10];

    const int N = in_sizes[0] / D;
    const int E = in_sizes[2];
    const int* src = ei;
    const int* dst = ei + E;

    // workspace layout
    float* fws = (float*)d_ws;
    float* q  = fws;                   // N*D
    float* k  = q  + (size_t)N * D;
    float* v  = k  + (size_t)N * D;
    float* h0 = v  + (size_t)N * D;
    float* h1 = h0 + (size_t)N * D;
    int* esrc   = (int*)(h1 + (size_t)N * D);  // E
    int* counts = esrc + E;                    // N
    int* offs   = counts + N;                  // N
    int* cursor = offs + N;                    // N
    int* bsum   = cursor + N;                  // 512

    const int nb_scan = (N + 255) / 256;       // blocks for N-sized scans

    // ---- sort edges by dst (once per call; reused across layers) ----
    hipMemsetAsync(counts, 0, (size_t)N * 4, stream);
    hipMemsetAsync(cursor, 0, (size_t)N * 4, stream);
    hist_kernel<<<(E + 255) / 256, 256, 0, stream>>>(dst, counts, E);
    scan_block_kernel<<<nb_scan, 256, 0, stream>>>(counts, offs, bsum, N);
    scan_bsum_kernel<<<1, 512, 0, stream>>>(bsum, nb_scan);
    add_bsum_kernel<<<nb_scan, 256, 0, stream>>>(offs, bsum, N);
    scatter_kernel<<<(E + 255) / 256, 256, 0, stream>>>(src, dst, offs, cursor, esrc, E);

    const int proj_blocks = (N + 15) / 16;
    const int node_blocks = (N + 15) / 16;

    const float* cur = x;
    for (int l = 0; l < LAYERS; ++l) {
        float* hout = (l == LAYERS - 1) ? (float*)d_out : (l & 1 ? h1 : h0);

        proj_kernel<<<proj_blocks, 256, 0, stream>>>(
            cur,
            Wq + (size_t)l * D * D, bq + (size_t)l * D,
            Wk + (size_t)l * D * D, bk + (size_t)l * D,
            Wv + (size_t)l * D * D, bv + (size_t)l * D,
            Ws + (size_t)l * D * D, bs + (size_t)l * D,
            q, k, v, hout, N);

        node_kernel<<<node_blocks, 256, 0, stream>>>(
            q, k, v, esrc, offs, counts, hout, N, l < LAYERS - 1 ? 1 : 0);

        cur = hout;
    }
}

// Round 3
// 723.855 us; speedup vs baseline: 6.7745x; 1.0178x over previous
//
#include <hip/hip_runtime.h>

#define D 64
#define LAYERS 3

// ---------------- projections ----------------
// q = x@Wq+bq, k = x@Wk+bk, v = x@Wv+bv, skip = x@Ws+bs (skip -> hout).
// 32 rows of x per block; each thread computes 8 rows x 1 col.
__global__ __launch_bounds__(256) void proj_kernel(
    const float* __restrict__ x,
    const float* __restrict__ Wq, const float* __restrict__ bq,
    const float* __restrict__ Wk, const float* __restrict__ bk,
    const float* __restrict__ Wv, const float* __restrict__ bv,
    const float* __restrict__ Ws, const float* __restrict__ bs,
    float* __restrict__ q, float* __restrict__ k,
    float* __restrict__ v, float* __restrict__ hout, int N)
{
    __shared__ float xs[32][D];
    const int block_row = blockIdx.x * 32;
    const int t = threadIdx.x;
    for (int i = t; i < 32 * D; i += 256) {
        int r = i >> 6, c = i & 63;
        int row = block_row + r;
        xs[r][c] = (row < N) ? x[row * D + c] : 0.0f;
    }
    __syncthreads();

    const int col  = t & 63;
    const int rsub = t >> 6;          // 0..3 -> rows rsub*8 .. rsub*8+7
    float aq[8], ak[8], av[8], as_[8];
    const float bqc = bq[col], bkc = bk[col], bvc = bv[col], bsc = bs[col];
#pragma unroll
    for (int j = 0; j < 8; ++j) { aq[j] = bqc; ak[j] = bkc; av[j] = bvc; as_[j] = bsc; }

    for (int i = 0; i < D; ++i) {
        const float wq = Wq[i * D + col];
        const float wk = Wk[i * D + col];
        const float wv = Wv[i * D + col];
        const float ws = Ws[i * D + col];
#pragma unroll
        for (int j = 0; j < 8; ++j) {
            const float xi = xs[rsub * 8 + j][i];
            aq[j]  = fmaf(xi, wq, aq[j]);
            ak[j]  = fmaf(xi, wk, ak[j]);
            av[j]  = fmaf(xi, wv, av[j]);
            as_[j] = fmaf(xi, ws, as_[j]);
        }
    }
#pragma unroll
    for (int j = 0; j < 8; ++j) {
        const int row = block_row + rsub * 8 + j;
        if (row < N) {
            q[row * D + col]    = aq[j];
            k[row * D + col]    = ak[j];
            v[row * D + col]    = av[j];
            hout[row * D + col] = as_[j];
        }
    }
}

// ---------------- counting sort of edges by dst ----------------
__global__ __launch_bounds__(256) void hist_kernel(
    const int* __restrict__ dst, int* __restrict__ counts, int E)
{
    const int e = blockIdx.x * 256 + threadIdx.x;
    if (e < E) atomicAdd(counts + dst[e], 1);
}

__global__ __launch_bounds__(256) void scan_block_kernel(
    const int* __restrict__ counts, int* __restrict__ offs,
    int* __restrict__ bsum, int N)
{
    __shared__ int tmp[256];
    const int t = threadIdx.x;
    const int i = blockIdx.x * 256 + t;
    const int val = (i < N) ? counts[i] : 0;
    tmp[t] = val;
    __syncthreads();
    for (int off = 1; off < 256; off <<= 1) {
        int x = (t >= off) ? tmp[t - off] : 0;
        __syncthreads();
        tmp[t] += x;
        __syncthreads();
    }
    if (i < N) offs[i] = tmp[t] - val;      // exclusive
    if (t == 255) bsum[blockIdx.x] = tmp[255];
}

__global__ __launch_bounds__(512) void scan_bsum_kernel(int* __restrict__ bsum, int nb)
{
    __shared__ int tmp[512];
    const int t = threadIdx.x;
    const int val = (t < nb) ? bsum[t] : 0;
    tmp[t] = val;
    __syncthreads();
    for (int off = 1; off < 512; off <<= 1) {
        int x = (t >= off) ? tmp[t - off] : 0;
        __syncthreads();
        tmp[t] += x;
        __syncthreads();
    }
    if (t < nb) bsum[t] = tmp[t] - val;     // exclusive
}

__global__ __launch_bounds__(256) void add_bsum_kernel(
    int* __restrict__ offs, const int* __restrict__ bsum, int N)
{
    const int i = blockIdx.x * 256 + threadIdx.x;
    if (i < N) offs[i] += bsum[blockIdx.x];
}

__global__ __launch_bounds__(256) void scatter_kernel(
    const int* __restrict__ src, const int* __restrict__ dst,
    const int* __restrict__ offs, int* __restrict__ cursor,
    int* __restrict__ esrc, int E)
{
    const int e = blockIdx.x * 256 + threadIdx.x;
    if (e >= E) return;
    const int d = dst[e];
    const int pos = offs[d] + atomicAdd(cursor + d, 1);
    esrc[pos] = src[e];
}

// ---------------- fused per-node attention ----------------
// 16 lanes per node (4 nodes/wave), dst-sorted edges, online softmax,
// 2-way edge unroll for MLP. hout already holds the skip term.
__global__ __launch_bounds__(256) void node_kernel(
    const float* __restrict__ q, const float* __restrict__ k,
    const float* __restrict__ v, const int* __restrict__ esrc,
    const int* __restrict__ offs, const int* __restrict__ counts,
    float* __restrict__ hout, int N, int do_relu)
{
    const int t = threadIdx.x;
    const int lane = t & 15;
    const int node = blockIdx.x * 16 + (t >> 4);
    if (node >= N) return;

    const int start = offs[node];
    const int end   = start + counts[node];

    const float4 qv = *(const float4*)(q + (size_t)node * D + lane * 4);

    float m = -INFINITY, ssum = 0.0f;
    float4 acc = make_float4(0.0f, 0.0f, 0.0f, 0.0f);

    int j = start;
    for (; j + 2 <= end; j += 2) {
        const int s0 = esrc[j];
        const int s1 = esrc[j + 1];
        const float4 k0 = *(const float4*)(k + (size_t)s0 * D + lane * 4);
        const float4 k1 = *(const float4*)(k + (size_t)s1 * D + lane * 4);
        const float4 v0 = *(const float4*)(v + (size_t)s0 * D + lane * 4);
        const float4 v1 = *(const float4*)(v + (size_t)s1 * D + lane * 4);

        float p0 = k0.x * qv.x + k0.y * qv.y + k0.z * qv.z + k0.w * qv.w;
        float p1 = k1.x * qv.x + k1.y * qv.y + k1.z * qv.z + k1.w * qv.w;
        p0 += __shfl_xor(p0, 1);  p1 += __shfl_xor(p1, 1);
        p0 += __shfl_xor(p0, 2);  p1 += __shfl_xor(p1, 2);
        p0 += __shfl_xor(p0, 4);  p1 += __shfl_xor(p1, 4);
        p0 += __shfl_xor(p0, 8);  p1 += __shfl_xor(p1, 8);
        p0 *= 0.125f;  p1 *= 0.125f;   // 1/sqrt(64)

        const float mx = fmaxf(p0, p1);
        if (mx > m) {                  // uniform across the 16-lane group
            const float sc = __expf(m - mx);   // 0 when m == -inf
            ssum *= sc;
            acc.x *= sc; acc.y *= sc; acc.z *= sc; acc.w *= sc;
            m = mx;
        }
        const float w0 = __expf(p0 - m);
        const float w1 = __expf(p1 - m);
        ssum += w0 + w1;
        acc.x = fmaf(w0, v0.x, fmaf(w1, v1.x, acc.x));
        acc.y = fmaf(w0, v0.y, fmaf(w1, v1.y, acc.y));
        acc.z = fmaf(w0, v0.z, fmaf(w1, v1.z, acc.z));
        acc.w = fmaf(w0, v0.w, fmaf(w1, v1.w, acc.w));
    }
    if (j < end) {                     // odd tail edge
        const int s0 = esrc[j];
        const float4 k0 = *(const float4*)(k + (size_t)s0 * D + lane * 4);
        const float4 v0 = *(const float4*)(v + (size_t)s0 * D + lane * 4);
        float p0 = k0.x * qv.x + k0.y * qv.y + k0.z * qv.z + k0.w * qv.w;
        p0 += __shfl_xor(p0, 1);
        p0 += __shfl_xor(p0, 2);
        p0 += __shfl_xor(p0, 4);
        p0 += __shfl_xor(p0, 8);
        p0 *= 0.125f;
        if (p0 > m) {
            const float sc = __expf(m - p0);
            ssum *= sc;
            acc.x *= sc; acc.y *= sc; acc.z *= sc; acc.w *= sc;
            m = p0;
        }
        const float w0 = __expf(p0 - m);
        ssum += w0;
        acc.x = fmaf(w0, v0.x, acc.x);
        acc.y = fmaf(w0, v0.y, acc.y);
        acc.z = fmaf(w0, v0.z, acc.z);
        acc.w = fmaf(w0, v0.w, acc.w);
    }

    const float inv = 1.0f / (ssum + 1e-16f);
    float* o = hout + (size_t)node * D + lane * 4;
    float4 ov = *(const float4*)o;
    ov.x = fmaf(acc.x, inv, ov.x);
    ov.y = fmaf(acc.y, inv, ov.y);
    ov.z = fmaf(acc.z, inv, ov.z);
    ov.w = fmaf(acc.w, inv, ov.w);
    if (do_relu) {
        ov.x = fmaxf(ov.x, 0.0f); ov.y = fmaxf(ov.y, 0.0f);
        ov.z = fmaxf(ov.z, 0.0f); ov.w = fmaxf(ov.w, 0.0f);
    }
    *(float4*)o = ov;
}

extern "C" void kernel_launch(void* const* d_in, const int* in_sizes, int n_in,
                              void* d_out, int out_size, void* d_ws, size_t ws_size,
                              hipStream_t stream)
{
    const float* x   = (const float*)d_in[0];
    const int* ei    = (const int*)d_in[1];
    const float* Wq  = (const float*)d_in[3];
    const float* bq  = (const float*)d_in[4];
    const float* Wk  = (const float*)d_in[5];
    const float* bk  = (const float*)d_in[6];
    const float* Wv  = (const float*)d_in[7];
    const float* bv  = (const float*)d_in[8];
    const float* Ws  = (const float*)d_in[9];
    const float* bs  = (const float*)d_in[10];

    const int N = in_sizes[0] / D;
    const int E = in_sizes[2];
    const int* src = ei;
    const int* dst = ei + E;

    // workspace layout
    float* fws = (float*)d_ws;
    float* q  = fws;                   // N*D
    float* k  = q  + (size_t)N * D;
    float* v  = k  + (size_t)N * D;
    float* h0 = v  + (size_t)N * D;
    float* h1 = h0 + (size_t)N * D;
    int* esrc   = (int*)(h1 + (size_t)N * D);  // E
    int* counts = esrc + E;                    // N
    int* offs   = counts + N;                  // N
    int* cursor = offs + N;                    // N
    int* bsum   = cursor + N;                  // 512

    const int nb_scan = (N + 255) / 256;

    // ---- sort edges by dst (once per call; reused across layers) ----
    hipMemsetAsync(counts, 0, (size_t)N * 4, stream);
    hipMemsetAsync(cursor, 0, (size_t)N * 4, stream);
    hist_kernel<<<(E + 255) / 256, 256, 0, stream>>>(dst, counts, E);
    scan_block_kernel<<<nb_scan, 256, 0, stream>>>(counts, offs, bsum, N);
    scan_bsum_kernel<<<1, 512, 0, stream>>>(bsum, nb_scan);
    add_bsum_kernel<<<nb_scan, 256, 0, stream>>>(offs, bsum, N);
    scatter_kernel<<<(E + 255) / 256, 256, 0, stream>>>(src, dst, offs, cursor, esrc, E);

    const int proj_blocks = (N + 31) / 32;
    const int node_blocks = (N + 15) / 16;

    const float* cur = x;
    for (int l = 0; l < LAYERS; ++l) {
        float* hout = (l == LAYERS - 1) ? (float*)d_out : (l & 1 ? h1 : h0);

        proj_kernel<<<proj_blocks, 256, 0, stream>>>(
            cur,
            Wq + (size_t)l * D * D, bq + (size_t)l * D,
            Wk + (size_t)l * D * D, bk + (size_t)l * D,
            Wv + (size_t)l * D * D, bv + (size_t)l * D,
            Ws + (size_t)l * D * D, bs + (size_t)l * D,
            q, k, v, hout, N);

        node_kernel<<<node_blocks, 256, 0, stream>>>(
            q, k, v, esrc, offs, counts, hout, N, l < LAYERS - 1 ? 1 : 0);

        cur = hout;
    }
}

// Round 4
// 561.023 us; speedup vs baseline: 8.7408x; 1.2902x over previous
//
#include <hip/hip_runtime.h>

#define D 64
#define LAYERS 3

typedef unsigned short ushort_t;

__device__ __forceinline__ ushort_t f2bf(float f) {           // RNE float->bf16
    unsigned b = __float_as_uint(f);
    b += 0x7FFFu + ((b >> 16) & 1u);
    return (ushort_t)(b >> 16);
}
__device__ __forceinline__ float bflo(unsigned u) { return __uint_as_float(u << 16); }
__device__ __forceinline__ float bfhi(unsigned u) { return __uint_as_float(u & 0xFFFF0000u); }

// ---------------- projections ----------------
// q = x@Wq+bq (fp32), skip = x@Ws+bs -> hout (fp32),
// k,v -> packed bf16 kv[N][128]: per 16-lane chunk g: elems [g*8..g*8+3]=k cols
// [4g..4g+3], [g*8+4..g*8+7]=v cols [4g..4g+3]. One uint4/lane covers k+v.
__global__ __launch_bounds__(256) void proj_kernel(
    const float* __restrict__ x,
    const float* __restrict__ Wq, const float* __restrict__ bq,
    const float* __restrict__ Wk, const float* __restrict__ bk,
    const float* __restrict__ Wv, const float* __restrict__ bv,
    const float* __restrict__ Ws, const float* __restrict__ bs,
    float* __restrict__ q, ushort_t* __restrict__ kv,
    float* __restrict__ hout, int N)
{
    __shared__ float xs[32][D];
    const int block_row = blockIdx.x * 32;
    const int t = threadIdx.x;
    for (int i = t; i < 32 * D; i += 256) {
        int r = i >> 6, c = i & 63;
        int row = block_row + r;
        xs[r][c] = (row < N) ? x[row * D + c] : 0.0f;
    }
    __syncthreads();

    const int col  = t & 63;
    const int rsub = t >> 6;          // 0..3 -> rows rsub*8 .. rsub*8+7
    float aq[8], ak[8], av[8], as_[8];
    const float bqc = bq[col], bkc = bk[col], bvc = bv[col], bsc = bs[col];
#pragma unroll
    for (int j = 0; j < 8; ++j) { aq[j] = bqc; ak[j] = bkc; av[j] = bvc; as_[j] = bsc; }

    for (int i = 0; i < D; ++i) {
        const float wq = Wq[i * D + col];
        const float wk = Wk[i * D + col];
        const float wv = Wv[i * D + col];
        const float ws = Ws[i * D + col];
#pragma unroll
        for (int j = 0; j < 8; ++j) {
            const float xi = xs[rsub * 8 + j][i];
            aq[j]  = fmaf(xi, wq, aq[j]);
            ak[j]  = fmaf(xi, wk, ak[j]);
            av[j]  = fmaf(xi, wv, av[j]);
            as_[j] = fmaf(xi, ws, as_[j]);
        }
    }
    const int g = col >> 2, r = col & 3;
#pragma unroll
    for (int j = 0; j < 8; ++j) {
        const int row = block_row + rsub * 8 + j;
        if (row < N) {
            q[row * D + col]    = aq[j];
            hout[row * D + col] = as_[j];
            ushort_t* kvr = kv + (size_t)row * 128;
            kvr[g * 8 + r]     = f2bf(ak[j]);
            kvr[g * 8 + 4 + r] = f2bf(av[j]);
        }
    }
}

// ---------------- counting sort of edges by dst ----------------
__global__ __launch_bounds__(256) void hist_kernel(
    const int* __restrict__ dst, int* __restrict__ counts, int E)
{
    const int e = blockIdx.x * 256 + threadIdx.x;
    if (e < E) atomicAdd(counts + dst[e], 1);
}

__global__ __launch_bounds__(256) void scan_block_kernel(
    const int* __restrict__ counts, int* __restrict__ offs,
    int* __restrict__ bsum, int N)
{
    __shared__ int tmp[256];
    const int t = threadIdx.x;
    const int i = blockIdx.x * 256 + t;
    const int val = (i < N) ? counts[i] : 0;
    tmp[t] = val;
    __syncthreads();
    for (int off = 1; off < 256; off <<= 1) {
        int x = (t >= off) ? tmp[t - off] : 0;
        __syncthreads();
        tmp[t] += x;
        __syncthreads();
    }
    if (i < N) offs[i] = tmp[t] - val;      // exclusive
    if (t == 255) bsum[blockIdx.x] = tmp[255];
}

__global__ __launch_bounds__(512) void scan_bsum_kernel(int* __restrict__ bsum, int nb)
{
    __shared__ int tmp[512];
    const int t = threadIdx.x;
    const int val = (t < nb) ? bsum[t] : 0;
    tmp[t] = val;
    __syncthreads();
    for (int off = 1; off < 512; off <<= 1) {
        int x = (t >= off) ? tmp[t - off] : 0;
        __syncthreads();
        tmp[t] += x;
        __syncthreads();
    }
    if (t < nb) bsum[t] = tmp[t] - val;     // exclusive
}

__global__ __launch_bounds__(256) void add_bsum_kernel(
    int* __restrict__ offs, const int* __restrict__ bsum, int N)
{
    const int i = blockIdx.x * 256 + threadIdx.x;
    if (i < N) offs[i] += bsum[blockIdx.x];
}

__global__ __launch_bounds__(256) void scatter_kernel(
    const int* __restrict__ src, const int* __restrict__ dst,
    const int* __restrict__ offs, int* __restrict__ cursor,
    int* __restrict__ esrc, int E)
{
    const int e = blockIdx.x * 256 + threadIdx.x;
    if (e >= E) return;
    const int d = dst[e];
    const int pos = offs[d] + atomicAdd(cursor + d, 1);
    esrc[pos] = src[e];
}

// ---------------- fused per-node attention ----------------
// 16 lanes/node, dst-sorted edges, online softmax, packed bf16 kv:
// one uint4 load per lane per edge = 256 B contiguous per edge.
__global__ __launch_bounds__(256) void node_kernel(
    const float* __restrict__ q, const uint4* __restrict__ kv,
    const int* __restrict__ esrc, const int* __restrict__ offs,
    const int* __restrict__ counts, float* __restrict__ hout,
    int N, int do_relu)
{
    const int t = threadIdx.x;
    const int lane = t & 15;
    const int node = blockIdx.x * 16 + (t >> 4);
    if (node >= N) return;

    const int start = offs[node];
    const int end   = start + counts[node];

    const float4 qv = *(const float4*)(q + (size_t)node * D + lane * 4);

    float m = -INFINITY, ssum = 0.0f;
    float4 acc = make_float4(0.0f, 0.0f, 0.0f, 0.0f);

    int j = start;
    for (; j + 2 <= end; j += 2) {
        const int s0 = esrc[j];
        const int s1 = esrc[j + 1];
        const uint4 u0 = kv[(size_t)s0 * 16 + lane];
        const uint4 u1 = kv[(size_t)s1 * 16 + lane];

        float p0 = bflo(u0.x) * qv.x + bfhi(u0.x) * qv.y
                 + bflo(u0.y) * qv.z + bfhi(u0.y) * qv.w;
        float p1 = bflo(u1.x) * qv.x + bfhi(u1.x) * qv.y
                 + bflo(u1.y) * qv.z + bfhi(u1.y) * qv.w;
        p0 += __shfl_xor(p0, 1);  p1 += __shfl_xor(p1, 1);
        p0 += __shfl_xor(p0, 2);  p1 += __shfl_xor(p1, 2);
        p0 += __shfl_xor(p0, 4);  p1 += __shfl_xor(p1, 4);
        p0 += __shfl_xor(p0, 8);  p1 += __shfl_xor(p1, 8);
        p0 *= 0.125f;  p1 *= 0.125f;   // 1/sqrt(64)

        const float mx = fmaxf(p0, p1);
        if (mx > m) {                  // uniform across the 16-lane group
            const float sc = __expf(m - mx);   // 0 when m == -inf
            ssum *= sc;
            acc.x *= sc; acc.y *= sc; acc.z *= sc; acc.w *= sc;
            m = mx;
        }
        const float w0 = __expf(p0 - m);
        const float w1 = __expf(p1 - m);
        ssum += w0 + w1;
        acc.x = fmaf(w0, bflo(u0.z), fmaf(w1, bflo(u1.z), acc.x));
        acc.y = fmaf(w0, bfhi(u0.z), fmaf(w1, bfhi(u1.z), acc.y));
        acc.z = fmaf(w0, bflo(u0.w), fmaf(w1, bflo(u1.w), acc.z));
        acc.w = fmaf(w0, bfhi(u0.w), fmaf(w1, bfhi(u1.w), acc.w));
    }
    if (j < end) {                     // odd tail edge
        const int s0 = esrc[j];
        const uint4 u0 = kv[(size_t)s0 * 16 + lane];
        float p0 = bflo(u0.x) * qv.x + bfhi(u0.x) * qv.y
                 + bflo(u0.y) * qv.z + bfhi(u0.y) * qv.w;
        p0 += __shfl_xor(p0, 1);
        p0 += __shfl_xor(p0, 2);
        p0 += __shfl_xor(p0, 4);
        p0 += __shfl_xor(p0, 8);
        p0 *= 0.125f;
        if (p0 > m) {
            const float sc = __expf(m - p0);
            ssum *= sc;
            acc.x *= sc; acc.y *= sc; acc.z *= sc; acc.w *= sc;
            m = p0;
        }
        const float w0 = __expf(p0 - m);
        ssum += w0;
        acc.x = fmaf(w0, bflo(u0.z), acc.x);
        acc.y = fmaf(w0, bfhi(u0.z), acc.y);
        acc.z = fmaf(w0, bflo(u0.w), acc.z);
        acc.w = fmaf(w0, bfhi(u0.w), acc.w);
    }

    const float inv = 1.0f / (ssum + 1e-16f);
    float* o = hout + (size_t)node * D + lane * 4;
    float4 ov = *(const float4*)o;
    ov.x = fmaf(acc.x, inv, ov.x);
    ov.y = fmaf(acc.y, inv, ov.y);
    ov.z = fmaf(acc.z, inv, ov.z);
    ov.w = fmaf(acc.w, inv, ov.w);
    if (do_relu) {
        ov.x = fmaxf(ov.x, 0.0f); ov.y = fmaxf(ov.y, 0.0f);
        ov.z = fmaxf(ov.z, 0.0f); ov.w = fmaxf(ov.w, 0.0f);
    }
    *(float4*)o = ov;
}

extern "C" void kernel_launch(void* const* d_in, const int* in_sizes, int n_in,
                              void* d_out, int out_size, void* d_ws, size_t ws_size,
                              hipStream_t stream)
{
    const float* x   = (const float*)d_in[0];
    const int* ei    = (const int*)d_in[1];
    const float* Wq  = (const float*)d_in[3];
    const float* bq  = (const float*)d_in[4];
    const float* Wk  = (const float*)d_in[5];
    const float* bk  = (const float*)d_in[6];
    const float* Wv  = (const float*)d_in[7];
    const float* bv  = (const float*)d_in[8];
    const float* Ws  = (const float*)d_in[9];
    const float* bs  = (const float*)d_in[10];

    const int N = in_sizes[0] / D;
    const int E = in_sizes[2];
    const int* src = ei;
    const int* dst = ei + E;

    // workspace layout
    float* fws = (float*)d_ws;
    float* q     = fws;                        // N*D floats
    ushort_t* kv = (ushort_t*)(q + (size_t)N * D);  // N*128 bf16 (= N*64 floats)
    float* h0    = (float*)(kv + (size_t)N * 128);  // N*D
    float* h1    = h0 + (size_t)N * D;              // N*D
    int* esrc    = (int*)(h1 + (size_t)N * D);      // E
    int* counts  = esrc + E;                        // N
    int* offs    = counts + N;                      // N
    int* cursor  = offs + N;                        // N
    int* bsum    = cursor + N;                      // 512

    const int nb_scan = (N + 255) / 256;

    // ---- sort edges by dst (once per call; reused across layers) ----
    hipMemsetAsync(counts, 0, (size_t)N * 4, stream);
    hipMemsetAsync(cursor, 0, (size_t)N * 4, stream);
    hist_kernel<<<(E + 255) / 256, 256, 0, stream>>>(dst, counts, E);
    scan_block_kernel<<<nb_scan, 256, 0, stream>>>(counts, offs, bsum, N);
    scan_bsum_kernel<<<1, 512, 0, stream>>>(bsum, nb_scan);
    add_bsum_kernel<<<nb_scan, 256, 0, stream>>>(offs, bsum, N);
    scatter_kernel<<<(E + 255) / 256, 256, 0, stream>>>(src, dst, offs, cursor, esrc, E);

    const int proj_blocks = (N + 31) / 32;
    const int node_blocks = (N + 15) / 16;

    const float* cur = x;
    for (int l = 0; l < LAYERS; ++l) {
        float* hout = (l == LAYERS - 1) ? (float*)d_out : (l & 1 ? h1 : h0);

        proj_kernel<<<proj_blocks, 256, 0, stream>>>(
            cur,
            Wq + (size_t)l * D * D, bq + (size_t)l * D,
            Wk + (size_t)l * D * D, bk + (size_t)l * D,
            Wv + (size_t)l * D * D, bv + (size_t)l * D,
            Ws + (size_t)l * D * D, bs + (size_t)l * D,
            q, kv, hout, N);

        node_kernel<<<node_blocks, 256, 0, stream>>>(
            q, (const uint4*)kv, esrc, offs, counts, hout, N,
            l < LAYERS - 1 ? 1 : 0);

        cur = hout;
    }
}

// Round 5
// 439.465 us; speedup vs baseline: 11.1585x; 1.2766x over previous
//
#include <hip/hip_runtime.h>

#define D 64
#define LAYERS 3
#define BSHIFT 8                 // bucket = dst >> 8 (256 nodes per bucket)
#define NBMAX 512                // max buckets supported (N <= 131072)
#define CHUNK 4096               // edges per pass-1 block (256 thr x 16)

typedef unsigned short ushort_t;

__device__ __forceinline__ ushort_t f2bf(float f) {           // RNE float->bf16
    unsigned b = __float_as_uint(f);
    b += 0x7FFFu + ((b >> 16) & 1u);
    return (ushort_t)(b >> 16);
}
__device__ __forceinline__ float bflo(unsigned u) { return __uint_as_float(u << 16); }
__device__ __forceinline__ float bfhi(unsigned u) { return __uint_as_float(u & 0xFFFF0000u); }

// ---------------- projections ----------------
// q = x@Wq+bq (fp32), skip = x@Ws+bs -> hout (fp32),
// k,v -> packed bf16 kv[N][128]: chunk g holds k cols [4g..4g+3] then v cols.
__global__ __launch_bounds__(256) void proj_kernel(
    const float* __restrict__ x,
    const float* __restrict__ Wq, const float* __restrict__ bq,
    const float* __restrict__ Wk, const float* __restrict__ bk,
    const float* __restrict__ Wv, const float* __restrict__ bv,
    const float* __restrict__ Ws, const float* __restrict__ bs,
    float* __restrict__ q, ushort_t* __restrict__ kv,
    float* __restrict__ hout, int N)
{
    __shared__ float xs[32][D];
    const int block_row = blockIdx.x * 32;
    const int t = threadIdx.x;
    for (int i = t; i < 32 * D; i += 256) {
        int r = i >> 6, c = i & 63;
        int row = block_row + r;
        xs[r][c] = (row < N) ? x[row * D + c] : 0.0f;
    }
    __syncthreads();

    const int col  = t & 63;
    const int rsub = t >> 6;
    float aq[8], ak[8], av[8], as_[8];
    const float bqc = bq[col], bkc = bk[col], bvc = bv[col], bsc = bs[col];
#pragma unroll
    for (int j = 0; j < 8; ++j) { aq[j] = bqc; ak[j] = bkc; av[j] = bvc; as_[j] = bsc; }

    for (int i = 0; i < D; ++i) {
        const float wq = Wq[i * D + col];
        const float wk = Wk[i * D + col];
        const float wv = Wv[i * D + col];
        const float ws = Ws[i * D + col];
#pragma unroll
        for (int j = 0; j < 8; ++j) {
            const float xi = xs[rsub * 8 + j][i];
            aq[j]  = fmaf(xi, wq, aq[j]);
            ak[j]  = fmaf(xi, wk, ak[j]);
            av[j]  = fmaf(xi, wv, av[j]);
            as_[j] = fmaf(xi, ws, as_[j]);
        }
    }
    const int g = col >> 2, r = col & 3;
#pragma unroll
    for (int j = 0; j < 8; ++j) {
        const int row = block_row + rsub * 8 + j;
        if (row < N) {
            q[row * D + col]    = aq[j];
            hout[row * D + col] = as_[j];
            ushort_t* kvr = kv + (size_t)row * 128;
            kvr[g * 8 + r]     = f2bf(ak[j]);
            kvr[g * 8 + 4 + r] = f2bf(av[j]);
        }
    }
}

// ---------------- two-pass bucketed counting sort ----------------
// P0: global bucket histogram (LDS-aggregated)
__global__ __launch_bounds__(256) void b_hist_kernel(
    const int* __restrict__ dst, int* __restrict__ bcount, int E)
{
    __shared__ int h[NBMAX];
    const int t = threadIdx.x;
    h[t] = 0; h[t + 256] = 0;
    __syncthreads();
    const int base = blockIdx.x * CHUNK;
#pragma unroll
    for (int i = 0; i < 16; ++i) {
        const int e = base + i * 256 + t;
        if (e < E) atomicAdd(h + (dst[e] >> BSHIFT), 1);
    }
    __syncthreads();
    if (h[t])       atomicAdd(bcount + t, h[t]);
    if (h[t + 256]) atomicAdd(bcount + t + 256, h[t + 256]);
}

// P0b: exclusive scan of bucket counts -> bbase[0..NBMAX], gcursor = bbase
__global__ __launch_bounds__(512) void b_scan_kernel(
    const int* __restrict__ bcount, int* __restrict__ bbase,
    int* __restrict__ gcursor, int E)
{
    __shared__ int tmp[NBMAX];
    const int t = threadIdx.x;
    const int val = bcount[t];
    tmp[t] = val;
    __syncthreads();
    for (int off = 1; off < NBMAX; off <<= 1) {
        int x = (t >= off) ? tmp[t - off] : 0;
        __syncthreads();
        tmp[t] += x;
        __syncthreads();
    }
    const int excl = tmp[t] - val;
    bbase[t] = excl;
    gcursor[t] = excl;
    if (t == NBMAX - 1) bbase[NBMAX] = E;
}

// P1: scatter (src,dst) into bucket-contiguous packed[] regions.
__global__ __launch_bounds__(256) void b_scatter_kernel(
    const int* __restrict__ src, const int* __restrict__ dst,
    int* __restrict__ gcursor, uint2* __restrict__ packed, int E)
{
    __shared__ int h[NBMAX];
    __shared__ int gb[NBMAX];
    const int t = threadIdx.x;
    h[t] = 0; h[t + 256] = 0;
    __syncthreads();

    const int base = blockIdx.x * CHUNK;
    int ls[16], ld[16], lr[16];
#pragma unroll
    for (int i = 0; i < 16; ++i) {
        const int e = base + i * 256 + t;
        if (e < E) {
            ls[i] = src[e];
            ld[i] = dst[e];
            lr[i] = atomicAdd(h + (ld[i] >> BSHIFT), 1);   // local rank
        }
    }
    __syncthreads();
    for (int b = t; b < NBMAX; b += 256) {
        const int c = h[b];
        gb[b] = c ? atomicAdd(gcursor + b, c) : 0;
    }
    __syncthreads();
#pragma unroll
    for (int i = 0; i < 16; ++i) {
        const int e = base + i * 256 + t;
        if (e < E) {
            const int pos = gb[ld[i] >> BSHIFT] + lr[i];
            packed[pos] = make_uint2((unsigned)ls[i], (unsigned)ld[i]);
        }
    }
}

// P2: one block per bucket. Two-sweep: node histogram -> offs/counts, then
// scatter src into esrc within the bucket's contiguous window.
__global__ __launch_bounds__(256) void b_final_kernel(
    const uint2* __restrict__ packed, const int* __restrict__ bbase,
    int* __restrict__ esrc, int* __restrict__ offs, int* __restrict__ counts,
    int N)
{
    __shared__ int hist[256];
    __shared__ int scan[256];
    __shared__ int cursor[256];
    const int t = threadIdx.x;
    const int b = blockIdx.x;
    const int s = bbase[b];
    const int e = bbase[b + 1];

    hist[t] = 0;
    __syncthreads();
    for (int j = s + t; j < e; j += 256) {
        atomicAdd(hist + (packed[j].y & 255), 1);
    }
    __syncthreads();
    const int val = hist[t];
    scan[t] = val;
    __syncthreads();
    for (int off = 1; off < 256; off <<= 1) {
        int x = (t >= off) ? scan[t - off] : 0;
        __syncthreads();
        scan[t] += x;
        __syncthreads();
    }
    const int excl = scan[t] - val;
    const int node = b * 256 + t;
    if (node < N) {
        counts[node] = val;
        offs[node]   = s + excl;
    }
    cursor[t] = excl;
    __syncthreads();
    for (int j = s + t; j < e; j += 256) {
        const uint2 p = packed[j];
        const int r = atomicAdd(cursor + (p.y & 255), 1);
        esrc[s + r] = (int)p.x;
    }
}

// ---------------- fused per-node attention ----------------
__global__ __launch_bounds__(256) void node_kernel(
    const float* __restrict__ q, const uint4* __restrict__ kv,
    const int* __restrict__ esrc, const int* __restrict__ offs,
    const int* __restrict__ counts, float* __restrict__ hout,
    int N, int do_relu)
{
    const int t = threadIdx.x;
    const int lane = t & 15;
    const int node = blockIdx.x * 16 + (t >> 4);
    if (node >= N) return;

    const int start = offs[node];
    const int end   = start + counts[node];

    const float4 qv = *(const float4*)(q + (size_t)node * D + lane * 4);

    float m = -INFINITY, ssum = 0.0f;
    float4 acc = make_float4(0.0f, 0.0f, 0.0f, 0.0f);

    int j = start;
    for (; j + 2 <= end; j += 2) {
        const int s0 = esrc[j];
        const int s1 = esrc[j + 1];
        const uint4 u0 = kv[(size_t)s0 * 16 + lane];
        const uint4 u1 = kv[(size_t)s1 * 16 + lane];

        float p0 = bflo(u0.x) * qv.x + bfhi(u0.x) * qv.y
                 + bflo(u0.y) * qv.z + bfhi(u0.y) * qv.w;
        float p1 = bflo(u1.x) * qv.x + bfhi(u1.x) * qv.y
                 + bflo(u1.y) * qv.z + bfhi(u1.y) * qv.w;
        p0 += __shfl_xor(p0, 1);  p1 += __shfl_xor(p1, 1);
        p0 += __shfl_xor(p0, 2);  p1 += __shfl_xor(p1, 2);
        p0 += __shfl_xor(p0, 4);  p1 += __shfl_xor(p1, 4);
        p0 += __shfl_xor(p0, 8);  p1 += __shfl_xor(p1, 8);
        p0 *= 0.125f;  p1 *= 0.125f;

        const float mx = fmaxf(p0, p1);
        if (mx > m) {
            const float sc = __expf(m - mx);
            ssum *= sc;
            acc.x *= sc; acc.y *= sc; acc.z *= sc; acc.w *= sc;
            m = mx;
        }
        const float w0 = __expf(p0 - m);
        const float w1 = __expf(p1 - m);
        ssum += w0 + w1;
        acc.x = fmaf(w0, bflo(u0.z), fmaf(w1, bflo(u1.z), acc.x));
        acc.y = fmaf(w0, bfhi(u0.z), fmaf(w1, bfhi(u1.z), acc.y));
        acc.z = fmaf(w0, bflo(u0.w), fmaf(w1, bflo(u1.w), acc.z));
        acc.w = fmaf(w0, bfhi(u0.w), fmaf(w1, bfhi(u1.w), acc.w));
    }
    if (j < end) {
        const int s0 = esrc[j];
        const uint4 u0 = kv[(size_t)s0 * 16 + lane];
        float p0 = bflo(u0.x) * qv.x + bfhi(u0.x) * qv.y
                 + bflo(u0.y) * qv.z + bfhi(u0.y) * qv.w;
        p0 += __shfl_xor(p0, 1);
        p0 += __shfl_xor(p0, 2);
        p0 += __shfl_xor(p0, 4);
        p0 += __shfl_xor(p0, 8);
        p0 *= 0.125f;
        if (p0 > m) {
            const float sc = __expf(m - p0);
            ssum *= sc;
            acc.x *= sc; acc.y *= sc; acc.z *= sc; acc.w *= sc;
            m = p0;
        }
        const float w0 = __expf(p0 - m);
        ssum += w0;
        acc.x = fmaf(w0, bflo(u0.z), acc.x);
        acc.y = fmaf(w0, bfhi(u0.z), acc.y);
        acc.z = fmaf(w0, bflo(u0.w), acc.z);
        acc.w = fmaf(w0, bfhi(u0.w), acc.w);
    }

    const float inv = 1.0f / (ssum + 1e-16f);
    float* o = hout + (size_t)node * D + lane * 4;
    float4 ov = *(const float4*)o;
    ov.x = fmaf(acc.x, inv, ov.x);
    ov.y = fmaf(acc.y, inv, ov.y);
    ov.z = fmaf(acc.z, inv, ov.z);
    ov.w = fmaf(acc.w, inv, ov.w);
    if (do_relu) {
        ov.x = fmaxf(ov.x, 0.0f); ov.y = fmaxf(ov.y, 0.0f);
        ov.z = fmaxf(ov.z, 0.0f); ov.w = fmaxf(ov.w, 0.0f);
    }
    *(float4*)o = ov;
}

extern "C" void kernel_launch(void* const* d_in, const int* in_sizes, int n_in,
                              void* d_out, int out_size, void* d_ws, size_t ws_size,
                              hipStream_t stream)
{
    const float* x   = (const float*)d_in[0];
    const int* ei    = (const int*)d_in[1];
    const float* Wq  = (const float*)d_in[3];
    const float* bq  = (const float*)d_in[4];
    const float* Wk  = (const float*)d_in[5];
    const float* bk  = (const float*)d_in[6];
    const float* Wv  = (const float*)d_in[7];
    const float* bv  = (const float*)d_in[8];
    const float* Ws  = (const float*)d_in[9];
    const float* bs  = (const float*)d_in[10];

    const int N = in_sizes[0] / D;
    const int E = in_sizes[2];
    const int* src = ei;
    const int* dst = ei + E;
    const int NB = (N + 255) / 256;       // buckets actually used (<= NBMAX)

    // workspace layout
    float* fws = (float*)d_ws;
    float* q     = fws;                             // N*D floats
    ushort_t* kv = (ushort_t*)(q + (size_t)N * D);  // N*128 bf16
    float* h0    = (float*)(kv + (size_t)N * 128);  // N*D
    float* h1    = h0 + (size_t)N * D;              // N*D
    int* esrc    = (int*)(h1 + (size_t)N * D);      // E
    uint2* packed = (uint2*)(esrc + E);             // E uint2
    int* counts  = (int*)(packed + E);              // NBMAX*256
    int* offs    = counts + NBMAX * 256;            // NBMAX*256
    int* bcount  = offs + NBMAX * 256;              // NBMAX
    int* bbase   = bcount + NBMAX;                  // NBMAX+1
    int* gcursor = bbase + NBMAX + 1;               // NBMAX

    // ---- sort edges by dst (once per call; reused across layers) ----
    hipMemsetAsync(bcount, 0, NBMAX * 4, stream);
    const int p1_blocks = (E + CHUNK - 1) / CHUNK;
    b_hist_kernel<<<p1_blocks, 256, 0, stream>>>(dst, bcount, E);
    b_scan_kernel<<<1, NBMAX, 0, stream>>>(bcount, bbase, gcursor, E);
    b_scatter_kernel<<<p1_blocks, 256, 0, stream>>>(src, dst, gcursor, packed, E);
    b_final_kernel<<<NB, 256, 0, stream>>>(packed, bbase, esrc, offs, counts, N);

    const int proj_blocks = (N + 31) / 32;
    const int node_blocks = (N + 15) / 16;

    const float* cur = x;
    for (int l = 0; l < LAYERS; ++l) {
        float* hout = (l == LAYERS - 1) ? (float*)d_out : (l & 1 ? h1 : h0);

        proj_kernel<<<proj_blocks, 256, 0, stream>>>(
            cur,
            Wq + (size_t)l * D * D, bq + (size_t)l * D,
            Wk + (size_t)l * D * D, bk + (size_t)l * D,
            Wv + (size_t)l * D * D, bv + (size_t)l * D,
            Ws + (size_t)l * D * D, bs + (size_t)l * D,
            q, kv, hout, N);

        node_kernel<<<node_blocks, 256, 0, stream>>>(
            q, (const uint4*)kv, esrc, offs, counts, hout, N,
            l < LAYERS - 1 ? 1 : 0);

        cur = hout;
    }
}

// Round 6
// 363.145 us; speedup vs baseline: 13.5036x; 1.2102x over previous
//
#include <hip/hip_runtime.h>

#define D 64
#define LAYERS 3
#define BSHIFT 8                 // bucket = dst >> 8 (256 nodes per bucket)
#define NBMAX 512                // max buckets supported (N <= 131072)
#define CHUNK 4096               // edges per pass-1 block (256 thr x 16)
#define WSTRIDE 72               // padded LDS row stride (ushorts) — kills bank conflicts

typedef unsigned short ushort_t;
typedef __bf16 bf16x8 __attribute__((ext_vector_type(8)));
typedef float f32x4 __attribute__((ext_vector_type(4)));

__device__ __forceinline__ ushort_t f2bf(float f) {           // RNE float->bf16
    unsigned b = __float_as_uint(f);
    b += 0x7FFFu + ((b >> 16) & 1u);
    return (ushort_t)(b >> 16);
}
__device__ __forceinline__ float bflo(unsigned u) { return __uint_as_float(u << 16); }
__device__ __forceinline__ float bfhi(unsigned u) { return __uint_as_float(u & 0xFFFF0000u); }

// ---------------- projections via MFMA ----------------
// Per block: 32 rows. Stage x-tile bf16 + all 4 W^T bf16 in LDS.
// Wave w computes x@W[w] for its matrix: 0=q, 1=k, 2=v, 3=skip.
// q,skip stored fp32; k,v stored into packed bf16 kv[N][128]
// (chunk g: [g*8..g*8+3]=k cols 4g..4g+3, [g*8+4..g*8+7]=v cols).
__global__ __launch_bounds__(256) void proj_kernel(
    const float* __restrict__ x,
    const float* __restrict__ Wq, const float* __restrict__ bq,
    const float* __restrict__ Wk, const float* __restrict__ bk,
    const float* __restrict__ Wv, const float* __restrict__ bv,
    const float* __restrict__ Ws, const float* __restrict__ bs,
    float* __restrict__ q, ushort_t* __restrict__ kv,
    float* __restrict__ hout, int N)
{
    __shared__ ushort_t xs[32 * WSTRIDE];
    __shared__ ushort_t wt[4 * 64 * WSTRIDE];

    const int t = threadIdx.x;
    const int block_row = blockIdx.x * 32;

    // stage x tile: 32 rows x 64 cols, fp32 -> bf16, one b128 write per thread
    {
        const int r  = t >> 3;           // 0..31
        const int c8 = (t & 7) * 8;      // 0,8,...,56
        const int row = block_row + r;
        float4 x0, x1;
        if (row < N) {
            x0 = *(const float4*)(x + (size_t)row * D + c8);
            x1 = *(const float4*)(x + (size_t)row * D + c8 + 4);
        } else {
            x0 = make_float4(0.f,0.f,0.f,0.f); x1 = x0;
        }
        uint4 u;
        u.x = (unsigned)f2bf(x0.x) | ((unsigned)f2bf(x0.y) << 16);
        u.y = (unsigned)f2bf(x0.z) | ((unsigned)f2bf(x0.w) << 16);
        u.z = (unsigned)f2bf(x1.x) | ((unsigned)f2bf(x1.y) << 16);
        u.w = (unsigned)f2bf(x1.z) | ((unsigned)f2bf(x1.w) << 16);
        *(uint4*)(xs + r * WSTRIDE + c8) = u;
    }
    // stage W^T: wt[m][n*WSTRIDE + k] = W_m[k*64 + n], fp32 -> bf16
    {
        const float* Wm[4] = {Wq, Wk, Wv, Ws};
#pragma unroll
        for (int m = 0; m < 4; ++m) {
            const float* W = Wm[m];
            ushort_t* wtm = wt + m * 64 * WSTRIDE;
#pragma unroll
            for (int i = 0; i < 16; ++i) {
                const int e = i * 256 + t;       // 0..4095
                const int k = e >> 6, n = e & 63;
                wtm[n * WSTRIDE + k] = f2bf(W[e]);
            }
        }
    }
    __syncthreads();

    const int l  = t & 63;
    const int w  = t >> 6;            // wave id: 0=q,1=k,2=v,3=skip
    const int lr = l & 15;            // row (A) / col (B,D) within tile
    const int lk = (l >> 4) * 8;      // k sub-offset

    // A fragments: a[rt][ks] -> rows rt*16+lr, k = ks*32 + lk + [0..7]
    bf16x8 afr[2][2];
#pragma unroll
    for (int rt = 0; rt < 2; ++rt)
#pragma unroll
        for (int ks = 0; ks < 2; ++ks)
            afr[rt][ks] = *(const bf16x8*)(xs + (rt*16 + lr) * WSTRIDE + ks*32 + lk);

    const ushort_t* wtw = wt + w * 64 * WSTRIDE;
    f32x4 acc[2][4];
#pragma unroll
    for (int rt = 0; rt < 2; ++rt)
#pragma unroll
        for (int ct = 0; ct < 4; ++ct)
            acc[rt][ct] = (f32x4){0.f, 0.f, 0.f, 0.f};

#pragma unroll
    for (int ct = 0; ct < 4; ++ct) {
        const bf16x8 b0 = *(const bf16x8*)(wtw + (ct*16 + lr) * WSTRIDE + lk);
        const bf16x8 b1 = *(const bf16x8*)(wtw + (ct*16 + lr) * WSTRIDE + 32 + lk);
        acc[0][ct] = __builtin_amdgcn_mfma_f32_16x16x32_bf16(afr[0][0], b0, acc[0][ct], 0, 0, 0);
        acc[0][ct] = __builtin_amdgcn_mfma_f32_16x16x32_bf16(afr[0][1], b1, acc[0][ct], 0, 0, 0);
        acc[1][ct] = __builtin_amdgcn_mfma_f32_16x16x32_bf16(afr[1][0], b0, acc[1][ct], 0, 0, 0);
        acc[1][ct] = __builtin_amdgcn_mfma_f32_16x16x32_bf16(afr[1][1], b1, acc[1][ct], 0, 0, 0);
    }

    const float* biasW = (w == 0) ? bq : (w == 1) ? bk : (w == 2) ? bv : bs;
    float bcol[4];
#pragma unroll
    for (int ct = 0; ct < 4; ++ct) bcol[ct] = biasW[ct*16 + lr];

#pragma unroll
    for (int rt = 0; rt < 2; ++rt) {
#pragma unroll
        for (int ct = 0; ct < 4; ++ct) {
#pragma unroll
            for (int r = 0; r < 4; ++r) {
                const int row = block_row + rt*16 + (l >> 4) * 4 + r;  // C/D: row=(l>>4)*4+reg
                const int col = ct*16 + lr;                            // C/D: col=l&15
                if (row < N) {
                    const float val = acc[rt][ct][r] + bcol[ct];
                    if (w == 0)      q[(size_t)row * D + col]    = val;
                    else if (w == 3) hout[(size_t)row * D + col] = val;
                    else {
                        ushort_t* kvr = kv + (size_t)row * 128;
                        kvr[(col >> 2) * 8 + ((w == 2) ? 4 : 0) + (col & 3)] = f2bf(val);
                    }
                }
            }
        }
    }
}

// ---------------- two-pass bucketed counting sort ----------------
__global__ __launch_bounds__(256) void b_hist_kernel(
    const int* __restrict__ dst, int* __restrict__ bcount, int E)
{
    __shared__ int h[NBMAX];
    const int t = threadIdx.x;
    h[t] = 0; h[t + 256] = 0;
    __syncthreads();
    const int base = blockIdx.x * CHUNK;
#pragma unroll
    for (int i = 0; i < 16; ++i) {
        const int e = base + i * 256 + t;
        if (e < E) atomicAdd(h + (dst[e] >> BSHIFT), 1);
    }
    __syncthreads();
    if (h[t])       atomicAdd(bcount + t, h[t]);
    if (h[t + 256]) atomicAdd(bcount + t + 256, h[t + 256]);
}

__global__ __launch_bounds__(512) void b_scan_kernel(
    const int* __restrict__ bcount, int* __restrict__ bbase,
    int* __restrict__ gcursor, int E)
{
    __shared__ int tmp[NBMAX];
    const int t = threadIdx.x;
    const int val = bcount[t];
    tmp[t] = val;
    __syncthreads();
    for (int off = 1; off < NBMAX; off <<= 1) {
        int x = (t >= off) ? tmp[t - off] : 0;
        __syncthreads();
        tmp[t] += x;
        __syncthreads();
    }
    const int excl = tmp[t] - val;
    bbase[t] = excl;
    gcursor[t] = excl;
    if (t == NBMAX - 1) bbase[NBMAX] = E;
}

__global__ __launch_bounds__(256) void b_scatter_kernel(
    const int* __restrict__ src, const int* __restrict__ dst,
    int* __restrict__ gcursor, uint2* __restrict__ packed, int E)
{
    __shared__ int h[NBMAX];
    __shared__ int gb[NBMAX];
    const int t = threadIdx.x;
    h[t] = 0; h[t + 256] = 0;
    __syncthreads();

    const int base = blockIdx.x * CHUNK;
    int ls[16], ld[16], lr[16];
#pragma unroll
    for (int i = 0; i < 16; ++i) {
        const int e = base + i * 256 + t;
        if (e < E) {
            ls[i] = src[e];
            ld[i] = dst[e];
            lr[i] = atomicAdd(h + (ld[i] >> BSHIFT), 1);
        }
    }
    __syncthreads();
    for (int b = t; b < NBMAX; b += 256) {
        const int c = h[b];
        gb[b] = c ? atomicAdd(gcursor + b, c) : 0;
    }
    __syncthreads();
#pragma unroll
    for (int i = 0; i < 16; ++i) {
        const int e = base + i * 256 + t;
        if (e < E) {
            const int pos = gb[ld[i] >> BSHIFT] + lr[i];
            packed[pos] = make_uint2((unsigned)ls[i], (unsigned)ld[i]);
        }
    }
}

__global__ __launch_bounds__(256) void b_final_kernel(
    const uint2* __restrict__ packed, const int* __restrict__ bbase,
    int* __restrict__ esrc, int* __restrict__ offs, int* __restrict__ counts,
    int N)
{
    __shared__ int hist[256];
    __shared__ int scan[256];
    __shared__ int cursor[256];
    const int t = threadIdx.x;
    const int b = blockIdx.x;
    const int s = bbase[b];
    const int e = bbase[b + 1];

    hist[t] = 0;
    __syncthreads();
    for (int j = s + t; j < e; j += 256) {
        atomicAdd(hist + (packed[j].y & 255), 1);
    }
    __syncthreads();
    const int val = hist[t];
    scan[t] = val;
    __syncthreads();
    for (int off = 1; off < 256; off <<= 1) {
        int x = (t >= off) ? scan[t - off] : 0;
        __syncthreads();
        scan[t] += x;
        __syncthreads();
    }
    const int excl = scan[t] - val;
    const int node = b * 256 + t;
    if (node < N) {
        counts[node] = val;
        offs[node]   = s + excl;
    }
    cursor[t] = excl;
    __syncthreads();
    for (int j = s + t; j < e; j += 256) {
        const uint2 p = packed[j];
        const int r = atomicAdd(cursor + (p.y & 255), 1);
        esrc[s + r] = (int)p.x;
    }
}

// ---------------- fused per-node attention ----------------
__global__ __launch_bounds__(256) void node_kernel(
    const float* __restrict__ q, const uint4* __restrict__ kv,
    const int* __restrict__ esrc, const int* __restrict__ offs,
    const int* __restrict__ counts, float* __restrict__ hout,
    int N, int do_relu)
{
    const int t = threadIdx.x;
    const int lane = t & 15;
    const int node = blockIdx.x * 16 + (t >> 4);
    if (node >= N) return;

    const int start = offs[node];
    const int end   = start + counts[node];

    const float4 qv = *(const float4*)(q + (size_t)node * D + lane * 4);

    float m = -INFINITY, ssum = 0.0f;
    float4 acc = make_float4(0.0f, 0.0f, 0.0f, 0.0f);

    int j = start;
    for (; j + 2 <= end; j += 2) {
        const int s0 = esrc[j];
        const int s1 = esrc[j + 1];
        const uint4 u0 = kv[(size_t)s0 * 16 + lane];
        const uint4 u1 = kv[(size_t)s1 * 16 + lane];

        float p0 = bflo(u0.x) * qv.x + bfhi(u0.x) * qv.y
                 + bflo(u0.y) * qv.z + bfhi(u0.y) * qv.w;
        float p1 = bflo(u1.x) * qv.x + bfhi(u1.x) * qv.y
                 + bflo(u1.y) * qv.z + bfhi(u1.y) * qv.w;
        p0 += __shfl_xor(p0, 1);  p1 += __shfl_xor(p1, 1);
        p0 += __shfl_xor(p0, 2);  p1 += __shfl_xor(p1, 2);
        p0 += __shfl_xor(p0, 4);  p1 += __shfl_xor(p1, 4);
        p0 += __shfl_xor(p0, 8);  p1 += __shfl_xor(p1, 8);
        p0 *= 0.125f;  p1 *= 0.125f;

        const float mx = fmaxf(p0, p1);
        if (mx > m) {
            const float sc = __expf(m - mx);
            ssum *= sc;
            acc.x *= sc; acc.y *= sc; acc.z *= sc; acc.w *= sc;
            m = mx;
        }
        const float w0 = __expf(p0 - m);
        const float w1 = __expf(p1 - m);
        ssum += w0 + w1;
        acc.x = fmaf(w0, bflo(u0.z), fmaf(w1, bflo(u1.z), acc.x));
        acc.y = fmaf(w0, bfhi(u0.z), fmaf(w1, bfhi(u1.z), acc.y));
        acc.z = fmaf(w0, bflo(u0.w), fmaf(w1, bflo(u1.w), acc.z));
        acc.w = fmaf(w0, bfhi(u0.w), fmaf(w1, bfhi(u1.w), acc.w));
    }
    if (j < end) {
        const int s0 = esrc[j];
        const uint4 u0 = kv[(size_t)s0 * 16 + lane];
        float p0 = bflo(u0.x) * qv.x + bfhi(u0.x) * qv.y
                 + bflo(u0.y) * qv.z + bfhi(u0.y) * qv.w;
        p0 += __shfl_xor(p0, 1);
        p0 += __shfl_xor(p0, 2);
        p0 += __shfl_xor(p0, 4);
        p0 += __shfl_xor(p0, 8);
        p0 *= 0.125f;
        if (p0 > m) {
            const float sc = __expf(m - p0);
            ssum *= sc;
            acc.x *= sc; acc.y *= sc; acc.z *= sc; acc.w *= sc;
            m = p0;
        }
        const float w0 = __expf(p0 - m);
        ssum += w0;
        acc.x = fmaf(w0, bflo(u0.z), acc.x);
        acc.y = fmaf(w0, bfhi(u0.z), acc.y);
        acc.z = fmaf(w0, bflo(u0.w), acc.z);
        acc.w = fmaf(w0, bfhi(u0.w), acc.w);
    }

    const float inv = 1.0f / (ssum + 1e-16f);
    float* o = hout + (size_t)node * D + lane * 4;
    float4 ov = *(const float4*)o;
    ov.x = fmaf(acc.x, inv, ov.x);
    ov.y = fmaf(acc.y, inv, ov.y);
    ov.z = fmaf(acc.z, inv, ov.z);
    ov.w = fmaf(acc.w, inv, ov.w);
    if (do_relu) {
        ov.x = fmaxf(ov.x, 0.0f); ov.y = fmaxf(ov.y, 0.0f);
        ov.z = fmaxf(ov.z, 0.0f); ov.w = fmaxf(ov.w, 0.0f);
    }
    *(float4*)o = ov;
}

extern "C" void kernel_launch(void* const* d_in, const int* in_sizes, int n_in,
                              void* d_out, int out_size, void* d_ws, size_t ws_size,
                              hipStream_t stream)
{
    const float* x   = (const float*)d_in[0];
    const int* ei    = (const int*)d_in[1];
    const float* Wq  = (const float*)d_in[3];
    const float* bq  = (const float*)d_in[4];
    const float* Wk  = (const float*)d_in[5];
    const float* bk  = (const float*)d_in[6];
    const float* Wv  = (const float*)d_in[7];
    const float* bv  = (const float*)d_in[8];
    const float* Ws  = (const float*)d_in[9];
    const float* bs  = (const float*)d_in[10];

    const int N = in_sizes[0] / D;
    const int E = in_sizes[2];
    const int* src = ei;
    const int* dst = ei + E;
    const int NB = (N + 255) / 256;

    // workspace layout
    float* fws = (float*)d_ws;
    float* q     = fws;                             // N*D floats
    ushort_t* kv = (ushort_t*)(q + (size_t)N * D);  // N*128 bf16
    float* h0    = (float*)(kv + (size_t)N * 128);  // N*D
    float* h1    = h0 + (size_t)N * D;              // N*D
    int* esrc    = (int*)(h1 + (size_t)N * D);      // E
    uint2* packed = (uint2*)(esrc + E);             // E uint2
    int* counts  = (int*)(packed + E);              // NBMAX*256
    int* offs    = counts + NBMAX * 256;            // NBMAX*256
    int* bcount  = offs + NBMAX * 256;              // NBMAX
    int* bbase   = bcount + NBMAX;                  // NBMAX+1
    int* gcursor = bbase + NBMAX + 1;               // NBMAX

    // ---- sort edges by dst (once per call; reused across layers) ----
    hipMemsetAsync(bcount, 0, NBMAX * 4, stream);
    const int p1_blocks = (E + CHUNK - 1) / CHUNK;
    b_hist_kernel<<<p1_blocks, 256, 0, stream>>>(dst, bcount, E);
    b_scan_kernel<<<1, NBMAX, 0, stream>>>(bcount, bbase, gcursor, E);
    b_scatter_kernel<<<p1_blocks, 256, 0, stream>>>(src, dst, gcursor, packed, E);
    b_final_kernel<<<NB, 256, 0, stream>>>(packed, bbase, esrc, offs, counts, N);

    const int proj_blocks = (N + 31) / 32;
    const int node_blocks = (N + 15) / 16;

    const float* cur = x;
    for (int l = 0; l < LAYERS; ++l) {
        float* hout = (l == LAYERS - 1) ? (float*)d_out : (l & 1 ? h1 : h0);

        proj_kernel<<<proj_blocks, 256, 0, stream>>>(
            cur,
            Wq + (size_t)l * D * D, bq + (size_t)l * D,
            Wk + (size_t)l * D * D, bk + (size_t)l * D,
            Wv + (size_t)l * D * D, bv + (size_t)l * D,
            Ws + (size_t)l * D * D, bs + (size_t)l * D,
            q, kv, hout, N);

        node_kernel<<<node_blocks, 256, 0, stream>>>(
            q, (const uint4*)kv, esrc, offs, counts, hout, N,
            l < LAYERS - 1 ? 1 : 0);

        cur = hout;
    }
}